// Round 1
// baseline (1463.116 us; speedup 1.0000x reference)
//
#include <hip/hip_runtime.h>

// Problem constants (fixed by the reference): N=100000, E=1600000.
// N % 8 == 0 and N % 4 == 0, so node-per-wave grids divide exactly and
// kernels containing __syncthreads have no ragged tail.

#define NEG_SLOPE 0.2f

// ---------------------------------------------------------------------------
// Encoder: per-node transformer over S=32 tokens, DIN=10 -> DM=6, NH=2, dh=3.
// 32 lanes per node (one token per lane), 8 nodes per 256-thread block.
// ---------------------------------------------------------------------------
__global__ void __launch_bounds__(256) encoder_kernel(
    const float* __restrict__ Xf,
    const float* __restrict__ Wq, const float* __restrict__ bq,
    const float* __restrict__ Wk, const float* __restrict__ bk,
    const float* __restrict__ Wv, const float* __restrict__ bv,
    const float* __restrict__ g0, const float* __restrict__ be0,
    const float* __restrict__ Wf1, const float* __restrict__ bf1,
    const float* __restrict__ Wf2, const float* __restrict__ bf2,
    const float* __restrict__ g1, const float* __restrict__ be1,
    const float* __restrict__ Wrep, const float* __restrict__ brep,
    float* __restrict__ xt, int n)
{
    int tid = threadIdx.x;
    int sub = tid >> 5;      // subgroup (node) within block, 0..7
    int s   = tid & 31;      // token index
    int v   = blockIdx.x * 8 + sub;
    if (v >= n) return;      // no barriers in this kernel -> safe

    const float* xp = Xf + (size_t)v * 320 + s * 10;
    float xv[10];
#pragma unroll
    for (int i = 0; i < 10; ++i) xv[i] = xp[i];

    float q[6], k[6], w[6];
#pragma unroll
    for (int j = 0; j < 6; ++j) { q[j] = bq[j]; k[j] = bk[j]; w[j] = bv[j]; }
#pragma unroll
    for (int i = 0; i < 10; ++i) {
#pragma unroll
        for (int j = 0; j < 6; ++j) {
            q[j] += xv[i] * Wq[i * 6 + j];
            k[j] += xv[i] * Wk[i * 6 + j];
            w[j] += xv[i] * Wv[i * 6 + j];
        }
    }

    const float scale = 0.40824829046386301637f;  // 1/sqrt(6)
    float O[6];
#pragma unroll
    for (int hh = 0; hh < 2; ++hh) {
        const int b = hh * 3;
        float m = -1e30f, l = 0.f, a0 = 0.f, a1 = 0.f, a2 = 0.f;
        for (int t = 0; t < 32; ++t) {
            float k0 = __shfl(k[b + 0], t, 32);
            float k1 = __shfl(k[b + 1], t, 32);
            float k2 = __shfl(k[b + 2], t, 32);
            float v0 = __shfl(w[b + 0], t, 32);
            float v1 = __shfl(w[b + 1], t, 32);
            float v2 = __shfl(w[b + 2], t, 32);
            float lg = (q[b] * k0 + q[b + 1] * k1 + q[b + 2] * k2) * scale;
            float nm = fmaxf(m, lg);
            float sc = expf(m - nm);
            float p  = expf(lg - nm);
            l  = l * sc + p;
            a0 = a0 * sc + p * v0;
            a1 = a1 * sc + p * v1;
            a2 = a2 * sc + p * v2;
            m  = nm;
        }
        float inv = 1.f / l;
        O[b + 0] = q[b + 0] + a0 * inv;
        O[b + 1] = q[b + 1] + a1 * inv;
        O[b + 2] = q[b + 2] + a2 * inv;
    }

    // LayerNorm(g0, be0)
    {
        float mean = (O[0] + O[1] + O[2] + O[3] + O[4] + O[5]) * (1.f / 6.f);
        float var = 0.f;
#pragma unroll
        for (int j = 0; j < 6; ++j) { float d = O[j] - mean; var += d * d; }
        var *= (1.f / 6.f);
        float r = 1.f / sqrtf(var + 1e-5f);
#pragma unroll
        for (int j = 0; j < 6; ++j) O[j] = (O[j] - mean) * r * g0[j] + be0[j];
    }

    // FFN 6 -> 24 -> 6, relu
    float f[6];
    {
        float hbuf[24];
#pragma unroll
        for (int r = 0; r < 24; ++r) {
            float t = bf1[r];
#pragma unroll
            for (int j = 0; j < 6; ++j) t += O[j] * Wf1[j * 24 + r];
            hbuf[r] = fmaxf(t, 0.f);
        }
#pragma unroll
        for (int j = 0; j < 6; ++j) {
            float t = bf2[j];
#pragma unroll
            for (int r = 0; r < 24; ++r) t += hbuf[r] * Wf2[r * 6 + j];
            f[j] = O[j] + t;
        }
    }
    // LayerNorm(g1, be1)
    {
        float mean = (f[0] + f[1] + f[2] + f[3] + f[4] + f[5]) * (1.f / 6.f);
        float var = 0.f;
#pragma unroll
        for (int j = 0; j < 6; ++j) { float d = f[j] - mean; var += d * d; }
        var *= (1.f / 6.f);
        float r = 1.f / sqrtf(var + 1e-5f);
#pragma unroll
        for (int j = 0; j < 6; ++j) f[j] = (f[j] - mean) * r * g1[j] + be1[j];
    }

    // xt[v, j] = sum_s f[s][j] * Wrep[s] + brep
    float wr = Wrep[s];
    float outv[6];
#pragma unroll
    for (int j = 0; j < 6; ++j) {
        float val = f[j] * wr;
#pragma unroll
        for (int off = 16; off >= 1; off >>= 1) val += __shfl_xor(val, off, 32);
        outv[j] = val;
    }
    if (s == 0) {
        float br = brep[0];
#pragma unroll
        for (int j = 0; j < 6; ++j) xt[(size_t)v * 6 + j] = outv[j] + br;
    }
}

// ---------------------------------------------------------------------------
// xw1 = x @ W1 (N,64); ai/aj per-node attention dot terms (N,8).
// One wave per node; lane = output column (h*8+c).
// ---------------------------------------------------------------------------
__global__ void __launch_bounds__(256) xw1_kernel(
    const float* __restrict__ x, const float* __restrict__ W1,
    const float* __restrict__ att1,
    float* __restrict__ xw, float* __restrict__ ai, float* __restrict__ aj, int n)
{
    int tid = threadIdx.x;
    int wv  = tid >> 6;
    int l   = tid & 63;
    int v   = blockIdx.x * 4 + wv;
    if (v >= n) return;

    const float* xp = x + (size_t)v * 64;
    float acc = 0.f;
#pragma unroll
    for (int kk = 0; kk < 64; ++kk) acc += xp[kk] * W1[kk * 64 + l];
    xw[(size_t)v * 64 + l] = acc;

    int h = l >> 3, c = l & 7;
    float pi = acc * att1[h * 16 + c];
    float pj = acc * att1[h * 16 + 8 + c];
#pragma unroll
    for (int off = 1; off < 8; off <<= 1) {
        pi += __shfl_xor(pi, off, 64);
        pj += __shfl_xor(pj, off, 64);
    }
    if (c == 0) {
        ai[(size_t)v * 8 + h] = pi;
        aj[(size_t)v * 8 + h] = pj;
    }
}

// ---------------------------------------------------------------------------
// CSR build: count -> scan -> scatter (by destination, excluding src==dst)
// ---------------------------------------------------------------------------
__global__ void count_kernel(const int* __restrict__ src, const int* __restrict__ dst,
                             int* __restrict__ deg, int e)
{
    int i = blockIdx.x * blockDim.x + threadIdx.x;
    if (i < e) {
        int s = src[i], d = dst[i];
        if (s != d) atomicAdd(&deg[d], 1);
    }
}

__global__ void __launch_bounds__(1024) scan_kernel(
    const int* __restrict__ deg, int* __restrict__ offsets, int n)
{
    __shared__ int sums[1024];
    int t = threadIdx.x;
    int ch = (n + 1023) >> 10;
    int start = t * ch;
    int end = min(start + ch, n);
    int local = 0;
    for (int i = start; i < end; ++i) local += deg[i];
    sums[t] = local;
    __syncthreads();
    for (int off = 1; off < 1024; off <<= 1) {
        int val = (t >= off) ? sums[t - off] : 0;
        __syncthreads();
        sums[t] += val;
        __syncthreads();
    }
    int run = sums[t] - local;  // exclusive prefix
    for (int i = start; i < end; ++i) { offsets[i] = run; run += deg[i]; }
}

__global__ void scatter_kernel(const int* __restrict__ src, const int* __restrict__ dst,
                               const int* __restrict__ offsets, int* __restrict__ cursor,
                               int* __restrict__ elist, int e)
{
    int i = blockIdx.x * blockDim.x + threadIdx.x;
    if (i < e) {
        int s = src[i], d = dst[i];
        if (s != d) {
            int pos = offsets[d] + atomicAdd(&cursor[d], 1);
            elist[pos] = s;
        }
    }
}

// ---------------------------------------------------------------------------
// GAT layer 1 aggregation: wave per node, lane = (h,c) of 8x8=64 outputs.
// h1 = elu(softmax-weighted sum of xw[src] + self loop, + b1)
// ---------------------------------------------------------------------------
__global__ void __launch_bounds__(256) agg1_kernel(
    const float* __restrict__ xw, const float* __restrict__ ai,
    const float* __restrict__ aj, const float* __restrict__ b1,
    const int* __restrict__ offs, const int* __restrict__ deg,
    const int* __restrict__ elist, float* __restrict__ h1out, int n)
{
    int tid = threadIdx.x;
    int wv  = tid >> 6;
    int l   = tid & 63;
    int v   = blockIdx.x * 4 + wv;
    if (v >= n) return;

    int h = l >> 3;
    float aiv = ai[(size_t)v * 8 + h];
    float a = aiv + aj[(size_t)v * 8 + h];          // self loop
    a = a >= 0.f ? a : NEG_SLOPE * a;
    float ea  = expf(a);
    float acc = ea * xw[(size_t)v * 64 + l];
    float den = ea;

    int off = offs[v], dg = deg[v];
    for (int j = 0; j < dg; ++j) {
        int sc = elist[off + j];
        float aa = aiv + aj[(size_t)sc * 8 + h];
        aa = aa >= 0.f ? aa : NEG_SLOPE * aa;
        float e2 = expf(aa);
        acc += e2 * xw[(size_t)sc * 64 + l];
        den += e2;
    }
    float o = acc / den + b1[l];
    h1out[(size_t)v * 64 + l] = o > 0.f ? o : expm1f(o);
}

// ---------------------------------------------------------------------------
// xw2 = concat(h1, xt) @ W2 (N,80) + per-node dots with att2 (N,8 each).
// Wave per node; lane handles output cols l and (l<16) 64+l.
// Requires n % 4 == 0 (true: N=100000).
// ---------------------------------------------------------------------------
__global__ void __launch_bounds__(256) xw2_kernel(
    const float* __restrict__ h1, const float* __restrict__ xt,
    const float* __restrict__ W2, const float* __restrict__ att2,
    float* __restrict__ xw2, float* __restrict__ ai, float* __restrict__ aj, int n)
{
    __shared__ float buf[4][80];
    int tid = threadIdx.x;
    int wv  = tid >> 6;
    int l   = tid & 63;
    int v   = blockIdx.x * 4 + wv;

    const float* hp = h1 + (size_t)v * 64;
    const float* xp = xt + (size_t)v * 6;
    float a0 = 0.f, a1 = 0.f;
#pragma unroll
    for (int kk = 0; kk < 70; ++kk) {
        float f = (kk < 64) ? hp[kk] : xp[kk - 64];
        a0 += f * W2[kk * 80 + l];
        if (l < 16) a1 += f * W2[kk * 80 + 64 + l];
    }
    xw2[(size_t)v * 80 + l] = a0;
    buf[wv][l] = a0;
    if (l < 16) { xw2[(size_t)v * 80 + 64 + l] = a1; buf[wv][64 + l] = a1; }
    __syncthreads();
    if (l < 16) {
        int h = l >> 1, wj = l & 1;
        float sdot = 0.f;
#pragma unroll
        for (int c = 0; c < 10; ++c) sdot += buf[wv][h * 10 + c] * att2[h * 20 + wj * 10 + c];
        if (wj == 0) ai[(size_t)v * 8 + h] = sdot;
        else         aj[(size_t)v * 8 + h] = sdot;
    }
}

// ---------------------------------------------------------------------------
// GAT layer 2 aggregation + head-mean + b2 + log_softmax.
// Wave per node; lane covers slot l (h=l/10,c=l%10) and slot 64+l for l<16.
// Requires n % 4 == 0.
// ---------------------------------------------------------------------------
__global__ void __launch_bounds__(256) agg2_kernel(
    const float* __restrict__ xw2, const float* __restrict__ ai,
    const float* __restrict__ aj, const float* __restrict__ b2,
    const int* __restrict__ offs, const int* __restrict__ deg,
    const int* __restrict__ elist, float* __restrict__ out, int n)
{
    __shared__ float buf[4][80];
    __shared__ float buf2[4][10];
    int tid = threadIdx.x;
    int wv  = tid >> 6;
    int l   = tid & 63;
    int v   = blockIdx.x * 4 + wv;

    int h0  = l / 10;
    int s1  = l + 64;
    int h1i = s1 / 10;

    float ai0  = ai[(size_t)v * 8 + h0];
    float aj0  = aj[(size_t)v * 8 + h0];
    float ai1v = (l < 16) ? ai[(size_t)v * 8 + h1i] : 0.f;
    float aj1v = (l < 16) ? aj[(size_t)v * 8 + h1i] : 0.f;
    float x0 = xw2[(size_t)v * 80 + l];
    float x1 = (l < 16) ? xw2[(size_t)v * 80 + s1] : 0.f;

    float t0 = ai0 + aj0;  t0 = t0 >= 0.f ? t0 : NEG_SLOPE * t0;
    float t1 = ai1v + aj1v; t1 = t1 >= 0.f ? t1 : NEG_SLOPE * t1;
    float e0 = expf(t0), e1 = expf(t1);
    float acc0 = e0 * x0, den0 = e0;
    float acc1 = e1 * x1, den1 = e1;

    int off = offs[v], dg = deg[v];
    for (int j = 0; j < dg; ++j) {
        int sc = elist[off + j];
        float a0 = ai0 + aj[(size_t)sc * 8 + h0];
        a0 = a0 >= 0.f ? a0 : NEG_SLOPE * a0;
        float ee0 = expf(a0);
        acc0 += ee0 * xw2[(size_t)sc * 80 + l];
        den0 += ee0;
        if (l < 16) {
            float a1 = ai1v + aj[(size_t)sc * 8 + h1i];
            a1 = a1 >= 0.f ? a1 : NEG_SLOPE * a1;
            float ee1 = expf(a1);
            acc1 += ee1 * xw2[(size_t)sc * 80 + s1];
            den1 += ee1;
        }
    }
    buf[wv][l] = acc0 / den0;
    if (l < 16) buf[wv][64 + l] = acc1 / den1;
    __syncthreads();
    if (l < 10) {
        float mval = 0.f;
#pragma unroll
        for (int hh = 0; hh < 8; ++hh) mval += buf[wv][hh * 10 + l];
        buf2[wv][l] = mval * 0.125f + b2[l];
    }
    __syncthreads();
    if (l < 10) {
        float mx = -1e30f;
#pragma unroll
        for (int c = 0; c < 10; ++c) mx = fmaxf(mx, buf2[wv][c]);
        float se = 0.f;
#pragma unroll
        for (int c = 0; c < 10; ++c) se += expf(buf2[wv][c] - mx);
        out[(size_t)v * 10 + l] = buf2[wv][l] - mx - logf(se);
    }
}

// ---------------------------------------------------------------------------
extern "C" void kernel_launch(void* const* d_in, const int* in_sizes, int n_in,
                              void* d_out, int out_size, void* d_ws, size_t ws_size,
                              hipStream_t stream)
{
    const float* x    = (const float*)d_in[0];
    const int*   ei   = (const int*)  d_in[1];
    const float* ef   = (const float*)d_in[2];
    const float* W1   = (const float*)d_in[3];
    const float* att1 = (const float*)d_in[4];
    const float* b1   = (const float*)d_in[5];
    const float* W2   = (const float*)d_in[6];
    const float* att2 = (const float*)d_in[7];
    const float* b2   = (const float*)d_in[8];
    const float* Wq   = (const float*)d_in[9];
    const float* bq   = (const float*)d_in[10];
    const float* Wk   = (const float*)d_in[11];
    const float* bk   = (const float*)d_in[12];
    const float* Wv   = (const float*)d_in[13];
    const float* bv   = (const float*)d_in[14];
    const float* g0   = (const float*)d_in[15];
    const float* be0  = (const float*)d_in[16];
    const float* Wf1  = (const float*)d_in[17];
    const float* bf1  = (const float*)d_in[18];
    const float* Wf2  = (const float*)d_in[19];
    const float* bf2  = (const float*)d_in[20];
    const float* g1   = (const float*)d_in[21];
    const float* be1  = (const float*)d_in[22];
    const float* Wrep = (const float*)d_in[23];
    const float* brep = (const float*)d_in[24];

    const int n = in_sizes[0] / 64;   // 100000
    const int e = in_sizes[1] / 2;    // 1600000
    const int* src = ei;
    const int* dst = ei + e;

    char* ws = (char*)d_ws;
    size_t o = 0;
    auto alloc = [&](size_t bytes) -> void* {
        void* p = ws + o;
        o += (bytes + 255) & ~(size_t)255;
        return p;
    };
    float* xw    = (float*)alloc((size_t)n * 80 * 4);  // xw1 (N,64) then xw2 (N,80)
    float* h1    = (float*)alloc((size_t)n * 64 * 4);
    float* ai    = (float*)alloc((size_t)n * 8 * 4);   // layer1 then layer2
    float* aj    = (float*)alloc((size_t)n * 8 * 4);
    float* xt    = (float*)alloc((size_t)n * 6 * 4);
    int*   deg   = (int*)  alloc((size_t)n * 4);
    int*   offs  = (int*)  alloc((size_t)n * 4);
    int*   cur   = (int*)  alloc((size_t)n * 4);
    int*   elist = (int*)  alloc((size_t)e * 4);
    (void)ws_size; (void)n_in; (void)out_size;

    hipMemsetAsync(deg, 0, (size_t)n * 4, stream);
    hipMemsetAsync(cur, 0, (size_t)n * 4, stream);

    encoder_kernel<<<n / 8, 256, 0, stream>>>(ef, Wq, bq, Wk, bk, Wv, bv, g0, be0,
                                              Wf1, bf1, Wf2, bf2, g1, be1, Wrep, brep,
                                              xt, n);
    xw1_kernel<<<n / 4, 256, 0, stream>>>(x, W1, att1, xw, ai, aj, n);
    count_kernel<<<(e + 255) / 256, 256, 0, stream>>>(src, dst, deg, e);
    scan_kernel<<<1, 1024, 0, stream>>>(deg, offs, n);
    scatter_kernel<<<(e + 255) / 256, 256, 0, stream>>>(src, dst, offs, cur, elist, e);
    agg1_kernel<<<n / 4, 256, 0, stream>>>(xw, ai, aj, b1, offs, deg, elist, h1, n);
    xw2_kernel<<<n / 4, 256, 0, stream>>>(h1, xt, W2, att2, xw, ai, aj, n);
    agg2_kernel<<<n / 4, 256, 0, stream>>>(xw, ai, aj, b2, offs, deg, elist,
                                           (float*)d_out, n);
}

// Round 2
// 1084.875 us; speedup vs baseline: 1.3487x; 1.3487x over previous
//
#include <hip/hip_runtime.h>

// N=100000 (divisible by 4,8,16), E=1600000. Grids divide exactly -> no guards,
// so kernels with __syncthreads have uniform control flow.

#define NEG_SLOPE 0.2f

// ---------------------------------------------------------------------------
// Encoder: per-node transformer over S=32 tokens, DIN=10 -> DM=6, NH=2, dh=3.
// 32 lanes per node, 8 nodes per 256-thread block. edge_feats staged via LDS
// with coalesced loads (10 KB/block).
// ---------------------------------------------------------------------------
__global__ void __launch_bounds__(256) encoder_kernel(
    const float* __restrict__ Xf,
    const float* __restrict__ Wq, const float* __restrict__ bq,
    const float* __restrict__ Wk, const float* __restrict__ bk,
    const float* __restrict__ Wv, const float* __restrict__ bv,
    const float* __restrict__ g0, const float* __restrict__ be0,
    const float* __restrict__ Wf1, const float* __restrict__ bf1,
    const float* __restrict__ Wf2, const float* __restrict__ bf2,
    const float* __restrict__ g1, const float* __restrict__ be1,
    const float* __restrict__ Wrep, const float* __restrict__ brep,
    float* __restrict__ xt, int n)
{
    __shared__ float sh[2560];
    int t = threadIdx.x;
    size_t base = (size_t)blockIdx.x * 2560;
#pragma unroll
    for (int i = 0; i < 10; ++i) sh[i * 256 + t] = Xf[base + i * 256 + t];
    __syncthreads();

    int sub = t >> 5;        // node within block
    int s   = t & 31;        // token
    int v   = blockIdx.x * 8 + sub;

    float xv[10];
#pragma unroll
    for (int i = 0; i < 10; ++i) xv[i] = sh[sub * 320 + s * 10 + i];

    float q[6], k[6], w[6];
#pragma unroll
    for (int j = 0; j < 6; ++j) { q[j] = bq[j]; k[j] = bk[j]; w[j] = bv[j]; }
#pragma unroll
    for (int i = 0; i < 10; ++i) {
#pragma unroll
        for (int j = 0; j < 6; ++j) {
            q[j] += xv[i] * Wq[i * 6 + j];
            k[j] += xv[i] * Wk[i * 6 + j];
            w[j] += xv[i] * Wv[i * 6 + j];
        }
    }

    // softmax logits have |.| << 1 -> no max subtraction needed
    const float scale = 0.40824829046386301637f;  // 1/sqrt(6)
    float O[6];
#pragma unroll
    for (int hh = 0; hh < 2; ++hh) {
        const int b = hh * 3;
        float l = 0.f, a0 = 0.f, a1 = 0.f, a2 = 0.f;
        for (int t2 = 0; t2 < 32; ++t2) {
            float k0 = __shfl(k[b + 0], t2, 32);
            float k1 = __shfl(k[b + 1], t2, 32);
            float k2 = __shfl(k[b + 2], t2, 32);
            float v0 = __shfl(w[b + 0], t2, 32);
            float v1 = __shfl(w[b + 1], t2, 32);
            float v2 = __shfl(w[b + 2], t2, 32);
            float lg = (q[b] * k0 + q[b + 1] * k1 + q[b + 2] * k2) * scale;
            float p  = expf(lg);
            l  += p;
            a0 += p * v0;
            a1 += p * v1;
            a2 += p * v2;
        }
        float inv = 1.f / l;
        O[b + 0] = q[b + 0] + a0 * inv;
        O[b + 1] = q[b + 1] + a1 * inv;
        O[b + 2] = q[b + 2] + a2 * inv;
    }

    // LayerNorm(g0, be0)
    {
        float mean = (O[0] + O[1] + O[2] + O[3] + O[4] + O[5]) * (1.f / 6.f);
        float var = 0.f;
#pragma unroll
        for (int j = 0; j < 6; ++j) { float d = O[j] - mean; var += d * d; }
        var *= (1.f / 6.f);
        float r = 1.f / sqrtf(var + 1e-5f);
#pragma unroll
        for (int j = 0; j < 6; ++j) O[j] = (O[j] - mean) * r * g0[j] + be0[j];
    }

    // FFN 6 -> 24 -> 6, relu, residual
    float f[6];
    {
        float hbuf[24];
#pragma unroll
        for (int r = 0; r < 24; ++r) {
            float tt = bf1[r];
#pragma unroll
            for (int j = 0; j < 6; ++j) tt += O[j] * Wf1[j * 24 + r];
            hbuf[r] = fmaxf(tt, 0.f);
        }
#pragma unroll
        for (int j = 0; j < 6; ++j) {
            float tt = bf2[j];
#pragma unroll
            for (int r = 0; r < 24; ++r) tt += hbuf[r] * Wf2[r * 6 + j];
            f[j] = O[j] + tt;
        }
    }
    // LayerNorm(g1, be1)
    {
        float mean = (f[0] + f[1] + f[2] + f[3] + f[4] + f[5]) * (1.f / 6.f);
        float var = 0.f;
#pragma unroll
        for (int j = 0; j < 6; ++j) { float d = f[j] - mean; var += d * d; }
        var *= (1.f / 6.f);
        float r = 1.f / sqrtf(var + 1e-5f);
#pragma unroll
        for (int j = 0; j < 6; ++j) f[j] = (f[j] - mean) * r * g1[j] + be1[j];
    }

    // xt[v, j] = sum_s f[s][j] * Wrep[s] + brep
    float wr = Wrep[s];
#pragma unroll
    for (int j = 0; j < 6; ++j) {
        float val = f[j] * wr;
#pragma unroll
        for (int off = 16; off >= 1; off >>= 1) val += __shfl_xor(val, off, 32);
        f[j] = val;
    }
    if (s == 0) {
        float br = brep[0];
#pragma unroll
        for (int j = 0; j < 6; ++j) xt[(size_t)v * 6 + j] = f[j] + br;
    }
}

// ---------------------------------------------------------------------------
// xw1 = x @ W1 (N,64) + per-node attention dots ai1/aj1 (N,8).
// W1 staged in LDS (16 KB). 4 waves/block, each wave does 4 nodes.
// x row loaded with ONE coalesced load, broadcast via LDS float4 reads.
// ---------------------------------------------------------------------------
__global__ void __launch_bounds__(256) xw1_kernel(
    const float* __restrict__ x, const float* __restrict__ W1,
    const float* __restrict__ att1,
    float* __restrict__ xw, float* __restrict__ ai, float* __restrict__ aj, int n)
{
    __shared__ float shW[4096];
    __shared__ float shX[4][64];
    int t = threadIdx.x, wv = t >> 6, l = t & 63;
#pragma unroll
    for (int i = 0; i < 16; ++i) shW[i * 256 + t] = W1[i * 256 + t];
    int h = l >> 3, c = l & 7;
    float a_i = att1[h * 16 + c];
    float a_j = att1[h * 16 + 8 + c];
    __syncthreads();

#pragma unroll
    for (int it = 0; it < 4; ++it) {
        int v = blockIdx.x * 16 + it * 4 + wv;
        shX[wv][l] = x[(size_t)v * 64 + l];
        float acc = 0.f;
#pragma unroll
        for (int k4 = 0; k4 < 16; ++k4) {
            float4 xb = *(const float4*)&shX[wv][k4 * 4];
            acc += xb.x * shW[(k4 * 4 + 0) * 64 + l];
            acc += xb.y * shW[(k4 * 4 + 1) * 64 + l];
            acc += xb.z * shW[(k4 * 4 + 2) * 64 + l];
            acc += xb.w * shW[(k4 * 4 + 3) * 64 + l];
        }
        xw[(size_t)v * 64 + l] = acc;

        float pi = acc * a_i;
        float pj = acc * a_j;
#pragma unroll
        for (int off = 1; off < 8; off <<= 1) {
            pi += __shfl_xor(pi, off, 64);
            pj += __shfl_xor(pj, off, 64);
        }
        if (c == 0) {
            ai[(size_t)v * 8 + h] = pi;
            aj[(size_t)v * 8 + h] = pj;
        }
    }
}

// ---------------------------------------------------------------------------
// CSR build: count -> scan -> scatter (by destination, excluding src==dst)
// ---------------------------------------------------------------------------
__global__ void count_kernel(const int* __restrict__ src, const int* __restrict__ dst,
                             int* __restrict__ deg, int e)
{
    int i = blockIdx.x * blockDim.x + threadIdx.x;
    if (i < e) {
        int s = src[i], d = dst[i];
        if (s != d) atomicAdd(&deg[d], 1);
    }
}

__global__ void __launch_bounds__(1024) scan_kernel(
    const int* __restrict__ deg, int* __restrict__ offsets, int n)
{
    __shared__ int sums[1024];
    int t = threadIdx.x;
    int ch = (n + 1023) >> 10;
    int start = t * ch;
    int end = min(start + ch, n);
    int local = 0;
    for (int i = start; i < end; ++i) local += deg[i];
    sums[t] = local;
    __syncthreads();
    for (int off = 1; off < 1024; off <<= 1) {
        int val = (t >= off) ? sums[t - off] : 0;
        __syncthreads();
        sums[t] += val;
        __syncthreads();
    }
    int run = sums[t] - local;  // exclusive prefix
    for (int i = start; i < end; ++i) { offsets[i] = run; run += deg[i]; }
}

__global__ void scatter_kernel(const int* __restrict__ src, const int* __restrict__ dst,
                               const int* __restrict__ offsets, int* __restrict__ cursor,
                               int* __restrict__ elist, int e)
{
    int i = blockIdx.x * blockDim.x + threadIdx.x;
    if (i < e) {
        int s = src[i], d = dst[i];
        if (s != d) {
            int pos = offsets[d] + atomicAdd(&cursor[d], 1);
            elist[pos] = s;
        }
    }
}

// ---------------------------------------------------------------------------
// Fused: GAT-1 aggregation (softmax gather) + ELU + xw2 = concat(h1,xt)@W2
// + layer-2 attention dots. h1 never touches global memory.
// 4 waves/block, 2 nodes per wave. W2 (22.4 KB) staged in LDS.
// ---------------------------------------------------------------------------
__global__ void __launch_bounds__(256) agg1_fused_kernel(
    const float* __restrict__ xw, const float* __restrict__ ai1,
    const float* __restrict__ aj1, const float* __restrict__ b1,
    const float* __restrict__ xt, const float* __restrict__ W2,
    const float* __restrict__ att2,
    const int* __restrict__ offs, const int* __restrict__ deg,
    const int* __restrict__ elist,
    float* __restrict__ xw2, float* __restrict__ ai2, float* __restrict__ aj2,
    int n)
{
    __shared__ float shW2[5600];
    __shared__ float shH[4][72];   // 64 h1 + 6 xt
    __shared__ float shR[4][80];
    int t = threadIdx.x, wv = t >> 6, l = t & 63;
    for (int i = t; i < 5600; i += 256) shW2[i] = W2[i];
    __syncthreads();

    int h = l >> 3;
    float b1l = b1[l];

#pragma unroll
    for (int it = 0; it < 2; ++it) {
        int v = blockIdx.x * 8 + it * 4 + wv;

        float aiv = ai1[(size_t)v * 8 + h];
        float a = aiv + aj1[(size_t)v * 8 + h];     // self loop
        a = a >= 0.f ? a : NEG_SLOPE * a;
        float ea  = expf(a);
        float acc = ea * xw[(size_t)v * 64 + l];
        float den = ea;

        int off = offs[v], dg = deg[v];
        int j = 0;
        for (; j + 4 <= dg; j += 4) {
            int s0 = elist[off + j + 0];
            int s1 = elist[off + j + 1];
            int s2 = elist[off + j + 2];
            int s3 = elist[off + j + 3];
            float p0 = aj1[(size_t)s0 * 8 + h];
            float p1 = aj1[(size_t)s1 * 8 + h];
            float p2 = aj1[(size_t)s2 * 8 + h];
            float p3 = aj1[(size_t)s3 * 8 + h];
            float y0 = xw[(size_t)s0 * 64 + l];
            float y1 = xw[(size_t)s1 * 64 + l];
            float y2 = xw[(size_t)s2 * 64 + l];
            float y3 = xw[(size_t)s3 * 64 + l];
            float t0 = aiv + p0; t0 = t0 >= 0.f ? t0 : NEG_SLOPE * t0;
            float t1 = aiv + p1; t1 = t1 >= 0.f ? t1 : NEG_SLOPE * t1;
            float t2 = aiv + p2; t2 = t2 >= 0.f ? t2 : NEG_SLOPE * t2;
            float t3 = aiv + p3; t3 = t3 >= 0.f ? t3 : NEG_SLOPE * t3;
            float e0 = expf(t0), e1 = expf(t1), e2 = expf(t2), e3 = expf(t3);
            acc += e0 * y0 + e1 * y1 + e2 * y2 + e3 * y3;
            den += e0 + e1 + e2 + e3;
        }
        for (; j < dg; ++j) {
            int sc = elist[off + j];
            float aa = aiv + aj1[(size_t)sc * 8 + h];
            aa = aa >= 0.f ? aa : NEG_SLOPE * aa;
            float e2 = expf(aa);
            acc += e2 * xw[(size_t)sc * 64 + l];
            den += e2;
        }

        float o = acc / den + b1l;
        o = o > 0.f ? o : expm1f(o);   // elu -> h1[v][l], stays on chip

        shH[wv][l] = o;
        if (l < 6) shH[wv][64 + l] = xt[(size_t)v * 6 + l];
        __syncthreads();

        // xw2 row = concat(h1, xt) @ W2 ; lane l -> cols l and (l<16) 64+l
        float a0 = 0.f, a1 = 0.f;
#pragma unroll
        for (int kk = 0; kk < 70; ++kk) {
            float f = shH[wv][kk];
            a0 += f * shW2[kk * 80 + l];
            if (l < 16) a1 += f * shW2[kk * 80 + 64 + l];
        }
        xw2[(size_t)v * 80 + l] = a0;
        shR[wv][l] = a0;
        if (l < 16) { xw2[(size_t)v * 80 + 64 + l] = a1; shR[wv][64 + l] = a1; }
        __syncthreads();

        if (l < 16) {
            int hh = l >> 1, wj = l & 1;
            float sdot = 0.f;
#pragma unroll
            for (int cc = 0; cc < 10; ++cc)
                sdot += shR[wv][hh * 10 + cc] * att2[hh * 20 + wj * 10 + cc];
            if (wj == 0) ai2[(size_t)v * 8 + hh] = sdot;
            else         aj2[(size_t)v * 8 + hh] = sdot;
        }
        __syncthreads();
    }
}

// ---------------------------------------------------------------------------
// GAT layer 2 aggregation + head-mean + b2 + log_softmax, batched edge loop.
// ---------------------------------------------------------------------------
__global__ void __launch_bounds__(256) agg2_kernel(
    const float* __restrict__ xw2, const float* __restrict__ ai,
    const float* __restrict__ aj, const float* __restrict__ b2,
    const int* __restrict__ offs, const int* __restrict__ deg,
    const int* __restrict__ elist, float* __restrict__ out, int n)
{
    __shared__ float buf[4][80];
    __shared__ float buf2[4][10];
    int tid = threadIdx.x;
    int wv  = tid >> 6;
    int l   = tid & 63;
    int v   = blockIdx.x * 4 + wv;

    int h0  = l / 10;
    int s1  = l + 64;
    int h1i = s1 / 10;

    float ai0  = ai[(size_t)v * 8 + h0];
    float aj0  = aj[(size_t)v * 8 + h0];
    float ai1v = (l < 16) ? ai[(size_t)v * 8 + h1i] : 0.f;
    float aj1v = (l < 16) ? aj[(size_t)v * 8 + h1i] : 0.f;
    float x0 = xw2[(size_t)v * 80 + l];
    float x1 = (l < 16) ? xw2[(size_t)v * 80 + s1] : 0.f;

    float t0 = ai0 + aj0;   t0 = t0 >= 0.f ? t0 : NEG_SLOPE * t0;
    float t1 = ai1v + aj1v; t1 = t1 >= 0.f ? t1 : NEG_SLOPE * t1;
    float e0 = expf(t0), e1 = expf(t1);
    float acc0 = e0 * x0, den0 = e0;
    float acc1 = e1 * x1, den1 = e1;

    int off = offs[v], dg = deg[v];
    int j = 0;
    for (; j + 4 <= dg; j += 4) {
        int s0_ = elist[off + j + 0];
        int s1_ = elist[off + j + 1];
        int s2_ = elist[off + j + 2];
        int s3_ = elist[off + j + 3];
        float p0 = aj[(size_t)s0_ * 8 + h0];
        float p1 = aj[(size_t)s1_ * 8 + h0];
        float p2 = aj[(size_t)s2_ * 8 + h0];
        float p3 = aj[(size_t)s3_ * 8 + h0];
        float y0 = xw2[(size_t)s0_ * 80 + l];
        float y1 = xw2[(size_t)s1_ * 80 + l];
        float y2 = xw2[(size_t)s2_ * 80 + l];
        float y3 = xw2[(size_t)s3_ * 80 + l];
        float q0 = 0.f, q1 = 0.f, q2 = 0.f, q3 = 0.f;
        float z0 = 0.f, z1 = 0.f, z2 = 0.f, z3 = 0.f;
        if (l < 16) {
            q0 = aj[(size_t)s0_ * 8 + h1i];
            q1 = aj[(size_t)s1_ * 8 + h1i];
            q2 = aj[(size_t)s2_ * 8 + h1i];
            q3 = aj[(size_t)s3_ * 8 + h1i];
            z0 = xw2[(size_t)s0_ * 80 + s1];
            z1 = xw2[(size_t)s1_ * 80 + s1];
            z2 = xw2[(size_t)s2_ * 80 + s1];
            z3 = xw2[(size_t)s3_ * 80 + s1];
        }
        float u0 = ai0 + p0; u0 = u0 >= 0.f ? u0 : NEG_SLOPE * u0;
        float u1 = ai0 + p1; u1 = u1 >= 0.f ? u1 : NEG_SLOPE * u1;
        float u2 = ai0 + p2; u2 = u2 >= 0.f ? u2 : NEG_SLOPE * u2;
        float u3 = ai0 + p3; u3 = u3 >= 0.f ? u3 : NEG_SLOPE * u3;
        float w0 = expf(u0), w1 = expf(u1), w2 = expf(u2), w3 = expf(u3);
        acc0 += w0 * y0 + w1 * y1 + w2 * y2 + w3 * y3;
        den0 += w0 + w1 + w2 + w3;
        float r0 = ai1v + q0; r0 = r0 >= 0.f ? r0 : NEG_SLOPE * r0;
        float r1 = ai1v + q1; r1 = r1 >= 0.f ? r1 : NEG_SLOPE * r1;
        float r2 = ai1v + q2; r2 = r2 >= 0.f ? r2 : NEG_SLOPE * r2;
        float r3 = ai1v + q3; r3 = r3 >= 0.f ? r3 : NEG_SLOPE * r3;
        float g0_ = expf(r0), g1_ = expf(r1), g2_ = expf(r2), g3_ = expf(r3);
        acc1 += g0_ * z0 + g1_ * z1 + g2_ * z2 + g3_ * z3;
        den1 += g0_ + g1_ + g2_ + g3_;
    }
    for (; j < dg; ++j) {
        int sc = elist[off + j];
        float a0 = ai0 + aj[(size_t)sc * 8 + h0];
        a0 = a0 >= 0.f ? a0 : NEG_SLOPE * a0;
        float ee0 = expf(a0);
        acc0 += ee0 * xw2[(size_t)sc * 80 + l];
        den0 += ee0;
        if (l < 16) {
            float a1 = ai1v + aj[(size_t)sc * 8 + h1i];
            a1 = a1 >= 0.f ? a1 : NEG_SLOPE * a1;
            float ee1 = expf(a1);
            acc1 += ee1 * xw2[(size_t)sc * 80 + s1];
            den1 += ee1;
        }
    }
    buf[wv][l] = acc0 / den0;
    if (l < 16) buf[wv][64 + l] = acc1 / den1;
    __syncthreads();
    if (l < 10) {
        float mval = 0.f;
#pragma unroll
        for (int hh = 0; hh < 8; ++hh) mval += buf[wv][hh * 10 + l];
        buf2[wv][l] = mval * 0.125f + b2[l];
    }
    __syncthreads();
    if (l < 10) {
        float mx = -1e30f;
#pragma unroll
        for (int cc = 0; cc < 10; ++cc) mx = fmaxf(mx, buf2[wv][cc]);
        float se = 0.f;
#pragma unroll
        for (int cc = 0; cc < 10; ++cc) se += expf(buf2[wv][cc] - mx);
        out[(size_t)v * 10 + l] = buf2[wv][l] - mx - logf(se);
    }
}

// ---------------------------------------------------------------------------
extern "C" void kernel_launch(void* const* d_in, const int* in_sizes, int n_in,
                              void* d_out, int out_size, void* d_ws, size_t ws_size,
                              hipStream_t stream)
{
    const float* x    = (const float*)d_in[0];
    const int*   ei   = (const int*)  d_in[1];
    const float* ef   = (const float*)d_in[2];
    const float* W1   = (const float*)d_in[3];
    const float* att1 = (const float*)d_in[4];
    const float* b1   = (const float*)d_in[5];
    const float* W2   = (const float*)d_in[6];
    const float* att2 = (const float*)d_in[7];
    const float* b2   = (const float*)d_in[8];
    const float* Wq   = (const float*)d_in[9];
    const float* bq   = (const float*)d_in[10];
    const float* Wk   = (const float*)d_in[11];
    const float* bk   = (const float*)d_in[12];
    const float* Wv   = (const float*)d_in[13];
    const float* bv   = (const float*)d_in[14];
    const float* g0   = (const float*)d_in[15];
    const float* be0  = (const float*)d_in[16];
    const float* Wf1  = (const float*)d_in[17];
    const float* bf1  = (const float*)d_in[18];
    const float* Wf2  = (const float*)d_in[19];
    const float* bf2  = (const float*)d_in[20];
    const float* g1   = (const float*)d_in[21];
    const float* be1  = (const float*)d_in[22];
    const float* Wrep = (const float*)d_in[23];
    const float* brep = (const float*)d_in[24];

    const int n = in_sizes[0] / 64;   // 100000
    const int e = in_sizes[1] / 2;    // 1600000
    const int* src = ei;
    const int* dst = ei + e;

    char* ws = (char*)d_ws;
    size_t o = 0;
    auto alloc = [&](size_t bytes) -> void* {
        void* p = ws + o;
        o += (bytes + 255) & ~(size_t)255;
        return p;
    };
    float* xw1b  = (float*)alloc((size_t)n * 64 * 4);
    float* xw2b  = (float*)alloc((size_t)n * 80 * 4);
    float* ai1   = (float*)alloc((size_t)n * 8 * 4);
    float* aj1   = (float*)alloc((size_t)n * 8 * 4);
    float* ai2   = (float*)alloc((size_t)n * 8 * 4);
    float* aj2   = (float*)alloc((size_t)n * 8 * 4);
    float* xt    = (float*)alloc((size_t)n * 6 * 4);
    int*   deg   = (int*)  alloc((size_t)n * 4);
    int*   offs  = (int*)  alloc((size_t)n * 4);
    int*   cur   = (int*)  alloc((size_t)n * 4);
    int*   elist = (int*)  alloc((size_t)e * 4);
    (void)ws_size; (void)n_in; (void)out_size;

    hipMemsetAsync(deg, 0, (size_t)n * 4, stream);
    hipMemsetAsync(cur, 0, (size_t)n * 4, stream);

    encoder_kernel<<<n / 8, 256, 0, stream>>>(ef, Wq, bq, Wk, bk, Wv, bv, g0, be0,
                                              Wf1, bf1, Wf2, bf2, g1, be1, Wrep, brep,
                                              xt, n);
    xw1_kernel<<<n / 16, 256, 0, stream>>>(x, W1, att1, xw1b, ai1, aj1, n);
    count_kernel<<<(e + 255) / 256, 256, 0, stream>>>(src, dst, deg, e);
    scan_kernel<<<1, 1024, 0, stream>>>(deg, offs, n);
    scatter_kernel<<<(e + 255) / 256, 256, 0, stream>>>(src, dst, offs, cur, elist, e);
    agg1_fused_kernel<<<n / 8, 256, 0, stream>>>(xw1b, ai1, aj1, b1, xt, W2, att2,
                                                 offs, deg, elist, xw2b, ai2, aj2, n);
    agg2_kernel<<<n / 4, 256, 0, stream>>>(xw2b, ai2, aj2, b2, offs, deg, elist,
                                           (float*)d_out, n);
}